// Round 1
// baseline (344.996 us; speedup 1.0000x reference)
//
#include <hip/hip_runtime.h>
#include <cstdint>
#include <cstddef>

typedef __attribute__((ext_vector_type(8)))  __bf16   bf16x8;
typedef __attribute__((ext_vector_type(4)))  float    f32x4;
typedef __attribute__((ext_vector_type(4)))  uint32_t u32x4;

#define N_ROWS   1179648   // 8*384*384
#define N_TILES  73728     // N_ROWS/16
#define N_WAVES  3072      // 768 blocks * 4 waves
#define SDIM     384
#define VOCAB    5

__device__ __forceinline__ uint32_t pack2_bf16(float lo, float hi){
  uint32_t a = __builtin_bit_cast(uint32_t, lo);
  uint32_t b = __builtin_bit_cast(uint32_t, hi);
  a += 0x7fffu + ((a >> 16) & 1u);          // RNE to bf16
  b += 0x7fffu + ((b >> 16) & 1u);
  return (a >> 16) | (b & 0xffff0000u);
}

// exact gelu: 0.5*x*(1+erf(x/sqrt(2))), A&S 7.1.26 erf, |err| <= 1.5e-7
__device__ __forceinline__ float gelu_exact(float x){
  float t  = 0.70710678118654752f * x;
  float a  = __builtin_fabsf(t);
  float k  = __builtin_amdgcn_rcpf(__builtin_fmaf(0.3275911f, a, 1.0f));
  float p  = __builtin_fmaf(1.061405429f, k, -1.453152027f);
  p = __builtin_fmaf(p, k, 1.421413741f);
  p = __builtin_fmaf(p, k, -0.284496736f);
  p = __builtin_fmaf(p, k, 0.254829592f);
  p = p * k;
  float e  = __expf(-(t * t));
  float er = __builtin_fmaf(-p, e, 1.0f);   // erf(|t|)
  er = __builtin_copysignf(er, t);
  float hx = 0.5f * x;
  return __builtin_fmaf(hx, er, hx);
}

__global__ __launch_bounds__(256, 3)
void mlp_kernel(const float* __restrict__ x,
                const float* __restrict__ W1, const float* __restrict__ b1,
                const float* __restrict__ W2, const float* __restrict__ b2,
                const float* __restrict__ W3, const float* __restrict__ b3,
                const float* __restrict__ lng, const float* __restrict__ lnb,
                const float* __restrict__ Wo,  const float* __restrict__ bo,
                float* __restrict__ tmp)
{
  // per-wave bounce buffer: 16 rows x 64 feats bf16 = 2KB (32 dwords/row), XOR-swizzled
  __shared__ uint32_t hB[4][16 * 32];

  const int tid  = threadIdx.x;
  const int wav  = tid >> 6;
  const int lane = tid & 63;
  const int h    = lane >> 4;   // k-block / feat-subrow selector
  const int b    = lane & 15;   // batch-row within tile (B/N index)
  const int swz  = (b & 7) << 2;  // dword-index XOR swizzle for bounce buffer

  uint32_t* myB = &hB[wav][0];

  // ---- preload W^T fragments into registers (A operand) ----
  // A[m][k], m = 16*mt + (lane&15) = out-feat, k = 32*s + 8*h + j = in-feat
  u32x4 wfrag[3][4][2];
  #pragma unroll
  for (int L = 0; L < 3; ++L) {
    const float* W = (L == 0) ? W1 : ((L == 1) ? W2 : W3);
    #pragma unroll
    for (int mt = 0; mt < 4; ++mt)
      #pragma unroll
      for (int s = 0; s < 2; ++s)
        #pragma unroll
        for (int w = 0; w < 4; ++w) {
          int k0 = 32 * s + 8 * h + 2 * w;
          float lo = W[(size_t)(k0    ) * 64 + 16 * mt + b];
          float hi = W[(size_t)(k0 + 1) * 64 + 16 * mt + b];
          wfrag[L][mt][s][w] = pack2_bf16(lo, hi);
        }
  }
  // Wo^T fragment (5 valid rows, padded to 16 with zeros)
  u32x4 wofrag[2];
  #pragma unroll
  for (int s = 0; s < 2; ++s)
    #pragma unroll
    for (int w = 0; w < 4; ++w) {
      int k0 = 32 * s + 8 * h + 2 * w;
      float lo = (b < VOCAB) ? Wo[(size_t)(k0    ) * VOCAB + b] : 0.0f;
      float hi = (b < VOCAB) ? Wo[(size_t)(k0 + 1) * VOCAB + b] : 0.0f;
      wofrag[s][w] = pack2_bf16(lo, hi);
    }

  const int gw = blockIdx.x * 4 + wav;  // 0..3071

  for (int t = gw; t < N_TILES; t += N_WAVES) {
    const int row0 = t * 16;

    // ---- load x tile as B fragments (x^T): B[k=in-feat][n=batch-row] ----
    u32x4 bf[2];
    #pragma unroll
    for (int s = 0; s < 2; ++s) {
      const float* px = x + (size_t)(row0 + b) * 64 + 32 * s + 8 * h;
      f32x4 x0 = *(const f32x4*)(px);
      f32x4 x1 = *(const f32x4*)(px + 4);
      bf[s][0] = pack2_bf16(x0[0], x0[1]);
      bf[s][1] = pack2_bf16(x0[2], x0[3]);
      bf[s][2] = pack2_bf16(x1[0], x1[1]);
      bf[s][3] = pack2_bf16(x1[2], x1[3]);
    }

    // ---- three (Linear -> gelu -> LN) blocks ----
    #pragma unroll
    for (int L = 0; L < 3; ++L) {
      const float* bias = (L == 0) ? b1 : ((L == 1) ? b2 : b3);
      f32x4 acc[4];
      #pragma unroll
      for (int mt = 0; mt < 4; ++mt) {
        // C init = bias (same for all batch cols): C[4h+r][b] = bias[16mt+4h+r]
        acc[mt] = *(const f32x4*)(bias + 16 * mt + 4 * h);
        acc[mt] = __builtin_amdgcn_mfma_f32_16x16x32_bf16(
            __builtin_bit_cast(bf16x8, wfrag[L][mt][0]),
            __builtin_bit_cast(bf16x8, bf[0]), acc[mt], 0, 0, 0);
        acc[mt] = __builtin_amdgcn_mfma_f32_16x16x32_bf16(
            __builtin_bit_cast(bf16x8, wfrag[L][mt][1]),
            __builtin_bit_cast(bf16x8, bf[1]), acc[mt], 0, 0, 0);
      }

      // gelu (exact) in fp32
      #pragma unroll
      for (int mt = 0; mt < 4; ++mt)
        #pragma unroll
        for (int r = 0; r < 4; ++r)
          acc[mt][r] = gelu_exact(acc[mt][r]);

      // LayerNorm over 64 feats of batch-row b: lane holds 16 feats,
      // other 48 live in lanes b+16, b+32, b+48 -> 2-step shfl_xor reduce
      float s1 = 0.0f, s2 = 0.0f;
      #pragma unroll
      for (int mt = 0; mt < 4; ++mt)
        #pragma unroll
        for (int r = 0; r < 4; ++r) {
          float v = acc[mt][r];
          s1 += v;
          s2 = __builtin_fmaf(v, v, s2);
        }
      s1 += __shfl_xor(s1, 16); s2 += __shfl_xor(s2, 16);
      s1 += __shfl_xor(s1, 32); s2 += __shfl_xor(s2, 32);
      float mu   = s1 * (1.0f / 64.0f);
      float var  = __builtin_fmaf(s2, (1.0f / 64.0f), -mu * mu);
      float rstd = rsqrtf(var + 1e-5f);
      float nm   = -mu * rstd;

      // normalize + affine, pack bf16, bounce through swizzled LDS,
      // then re-read as next-layer B fragments (same wave; no barrier needed)
      #pragma unroll
      for (int mt = 0; mt < 4; ++mt) {
        f32x4 gg = *(const f32x4*)(lng + 16 * mt + 4 * h);
        f32x4 bb = *(const f32x4*)(lnb + 16 * mt + 4 * h);
        float n0 = __builtin_fmaf(__builtin_fmaf(acc[mt][0], rstd, nm), gg[0], bb[0]);
        float n1 = __builtin_fmaf(__builtin_fmaf(acc[mt][1], rstd, nm), gg[1], bb[1]);
        float n2 = __builtin_fmaf(__builtin_fmaf(acc[mt][2], rstd, nm), gg[2], bb[2]);
        float n3 = __builtin_fmaf(__builtin_fmaf(acc[mt][3], rstd, nm), gg[3], bb[3]);
        // row b, feats 16mt+4h+{0..3}: dword q = 8mt+2h+{0,1}
        int di = (b * 32 + 8 * mt + 2 * h) ^ swz;
        myB[di]     = pack2_bf16(n0, n1);
        myB[di + 1] = pack2_bf16(n2, n3);
      }
      #pragma unroll
      for (int s = 0; s < 2; ++s) {
        int di = (b * 32 + 16 * s + 4 * h) ^ swz;   // feats 32s+8h.., 16B aligned
        u32x4 rb = *(const u32x4*)(myB + di);
        bf[s] = rb;
      }
    }

    // ---- output projection: out^T = Wo^T . h3^T (+ bo) ----
    f32x4 ao;
    #pragma unroll
    for (int r = 0; r < 4; ++r) {
      int v = 4 * h + r;
      ao[r] = (v < VOCAB) ? bo[v] : 0.0f;
    }
    ao = __builtin_amdgcn_mfma_f32_16x16x32_bf16(
        __builtin_bit_cast(bf16x8, wofrag[0]),
        __builtin_bit_cast(bf16x8, bf[0]), ao, 0, 0, 0);
    ao = __builtin_amdgcn_mfma_f32_16x16x32_bf16(
        __builtin_bit_cast(bf16x8, wofrag[1]),
        __builtin_bit_cast(bf16x8, bf[1]), ao, 0, 0, 0);

    float* dst = tmp + (size_t)(row0 + b) * VOCAB;
    #pragma unroll
    for (int r = 0; r < 4; ++r) {
      int v = 4 * h + r;
      if (v < VOCAB) dst[v] = ao[r];
    }
  }
}

__global__ __launch_bounds__(256)
void sym_kernel(const float* __restrict__ tmp, float* __restrict__ out)
{
  int t = blockIdx.x * 256 + threadIdx.x;   // one thread per (b,i,j)
  if (t >= N_ROWS) return;
  int j   = t % SDIM;
  int rem = t / SDIM;
  int i   = rem % SDIM;
  int bb  = rem / SDIM;
  const float* p = tmp + (size_t)t * VOCAB;
  const float* q = tmp + (size_t)((bb * SDIM + j) * SDIM + i) * VOCAB;
  float* o = out + (size_t)t * VOCAB;
  #pragma unroll
  for (int v = 0; v < VOCAB; ++v)
    o[v] = 0.5f * (p[v] + q[v]);
}

extern "C" void kernel_launch(void* const* d_in, const int* in_sizes, int n_in,
                              void* d_out, int out_size, void* d_ws, size_t ws_size,
                              hipStream_t stream)
{
  const float* x   = (const float*)d_in[0];
  const float* W1  = (const float*)d_in[1];
  const float* b1  = (const float*)d_in[2];
  const float* W2  = (const float*)d_in[3];
  const float* b2  = (const float*)d_in[4];
  const float* W3  = (const float*)d_in[5];
  const float* b3  = (const float*)d_in[6];
  const float* lng = (const float*)d_in[7];
  const float* lnb = (const float*)d_in[8];
  const float* Wo  = (const float*)d_in[9];
  const float* bo  = (const float*)d_in[10];

  float* tmp = (float*)d_ws;                 // needs 8*384*384*5*4 = 23.6 MB
  float* out = (float*)d_out;

  mlp_kernel<<<768, 256, 0, stream>>>(x, W1, b1, W2, b2, W3, b3,
                                      lng, lnb, Wo, bo, tmp);
  sym_kernel<<<N_ROWS / 256, 256, 0, stream>>>(tmp, out);
}